// Round 1
// baseline (294.498 us; speedup 1.0000x reference)
//
#include <hip/hip_runtime.h>

#define D_MODEL 1024
#define VOCAB   50257

// One block (256 threads = 4 waves) per batch row.
// Each lane holds 16 contiguous-by-wave floats of the input row (4x float4,
// coalesced: lane i reads float4 at [i], [i+64], [i+128], [i+192]).
// Wave w handles path levels k = w, w+4, w+8, ... Each level: gather weight
// row, fp32 dot, 64-lane butterfly reduce, stable log-sigmoid, accumulate.
// Final: 4 per-wave partials combined in LDS, single store. No atomics.
__global__ __launch_bounds__(256) void hs_kernel(
    const float* __restrict__ input,       // [B, D_MODEL]
    const float* __restrict__ W,           // [VOCAB-1, D_MODEL]
    const int*   __restrict__ path_nodes,  // [VOCAB, Dmax]
    const float* __restrict__ path_signs,  // [VOCAB, Dmax]
    const int*   __restrict__ target,      // [B]
    float*       __restrict__ out,         // [B]
    int Dmax)
{
    const int b    = blockIdx.x;
    const int tid  = threadIdx.x;
    const int lane = tid & 63;
    const int wave = tid >> 6;  // 0..3

    __shared__ int   s_nodes[64];
    __shared__ float s_signs[64];
    __shared__ float s_partial[4];

    const int t = target[b];
    if (tid < Dmax) {
        s_nodes[tid] = path_nodes[(long)t * Dmax + tid];
        s_signs[tid] = path_signs[(long)t * Dmax + tid];
    }
    __syncthreads();

    const float4* inp4 = reinterpret_cast<const float4*>(input + (long)b * D_MODEL);
    const float4 x0 = inp4[lane];
    const float4 x1 = inp4[lane + 64];
    const float4 x2 = inp4[lane + 128];
    const float4 x3 = inp4[lane + 192];

    float acc = 0.0f;
    for (int k = wave; k < Dmax; k += 4) {
        const float sgn = s_signs[k];
        if (sgn == 0.0f) continue;  // padding level
        const float4* w4 =
            reinterpret_cast<const float4*>(W + (long)s_nodes[k] * D_MODEL);
        const float4 w0 = w4[lane];
        const float4 w1 = w4[lane + 64];
        const float4 w2 = w4[lane + 128];
        const float4 w3 = w4[lane + 192];

        float dot = x0.x * w0.x + x0.y * w0.y + x0.z * w0.z + x0.w * w0.w
                  + x1.x * w1.x + x1.y * w1.y + x1.z * w1.z + x1.w * w1.w
                  + x2.x * w2.x + x2.y * w2.y + x2.z * w2.z + x2.w * w2.w
                  + x3.x * w3.x + x3.y * w3.y + x3.z * w3.z + x3.w * w3.w;

        // 64-lane butterfly reduce (all lanes end with the full dot).
        #pragma unroll
        for (int off = 32; off >= 1; off >>= 1)
            dot += __shfl_xor(dot, off);

        // stable log_sigmoid(sgn * dot)
        const float z = sgn * dot;
        acc += fminf(z, 0.0f) - log1pf(expf(-fabsf(z)));
    }

    if (lane == 0) s_partial[wave] = acc;
    __syncthreads();
    if (tid == 0)
        out[b] = s_partial[0] + s_partial[1] + s_partial[2] + s_partial[3];
}

extern "C" void kernel_launch(void* const* d_in, const int* in_sizes, int n_in,
                              void* d_out, int out_size, void* d_ws, size_t ws_size,
                              hipStream_t stream) {
    const float* input      = (const float*)d_in[0];
    const float* W          = (const float*)d_in[1];
    const int*   path_nodes = (const int*)d_in[2];
    const float* path_signs = (const float*)d_in[3];
    const int*   target     = (const int*)d_in[4];
    float*       out        = (float*)d_out;

    const int B    = in_sizes[4];
    const int Dmax = in_sizes[2] / VOCAB;

    hs_kernel<<<B, 256, 0, stream>>>(input, W, path_nodes, path_signs,
                                     target, out, Dmax);
}